// Round 6
// baseline (85.778 us; speedup 1.0000x reference)
//
#include <hip/hip_runtime.h>
#include <math.h>

#define EPS 1e-6f
#define IPB 2    // i per block

// fast sqrt / rcp: single v_sqrt_f32 / v_rcp_f32 (~1 ulp), skip IEEE fixup.
// Outputs compared at bf16 scale (absmax tol 0.0625) -> 1-ulp fp32 error invisible.
__device__ inline float fsqrt_fast(float x){ return __builtin_amdgcn_sqrtf(x); }
__device__ inline float frcp_fast(float x){ return __builtin_amdgcn_rcpf(x); }

struct F3 { float x, y, z; };
__device__ inline F3 sub3(F3 a, F3 b){return {a.x-b.x,a.y-b.y,a.z-b.z};}
__device__ inline float dot3(F3 a, F3 b){return a.x*b.x+a.y*b.y+a.z*b.z;}
__device__ inline F3 scale3(F3 a,float s){return {a.x*s,a.y*s,a.z*s};}
__device__ inline F3 cross3(F3 a,F3 b){return {a.y*b.z-a.z*b.y, a.z*b.x-a.x*b.z, a.x*b.y-a.y*b.x};}
__device__ inline F3 norm3(F3 v){float s=dot3(v,v);float inv=1.f/sqrtf(fmaxf(s,EPS));return scale3(v,inv);}

__device__ inline void make_frame(const float* __restrict__ base, float R[9], F3& ca) {
    F3 n = {base[0], base[1], base[2]};
    ca   = {base[3], base[4], base[5]};
    F3 c = {base[6], base[7], base[8]};
    F3 e1 = norm3(sub3(c, ca));
    F3 v2 = sub3(n, ca);
    float d = dot3(e1, v2);
    F3 e2 = norm3({v2.x - d*e1.x, v2.y - d*e1.y, v2.z - d*e1.z});
    F3 e3 = cross3(e1, e2);
    R[0]=e1.x; R[1]=e1.y; R[2]=e1.z;
    R[3]=e2.x; R[4]=e2.y; R[5]=e2.z;
    R[6]=e3.x; R[7]=e3.y; R[8]=e3.z;
}

// ---------------- prep + transpose fused ----------------
__global__ __launch_bounds__(256) void prep_all_kernel(
    const float* __restrict__ pred, const float* __restrict__ gt,
    const float* __restrict__ atom_mask, const int* __restrict__ batch,
    const int* __restrict__ chain,
    float* __restrict__ Mc, int* __restrict__ packed,
    float* __restrict__ gtca, float* __restrict__ predca,
    float4* __restrict__ predT4, float4* __restrict__ gtT4,
    int L, int N, int A)
{
    int idx = blockIdx.x * blockDim.x + threadIdx.x;

    // ---- transpose part: float4 slabs [a][j] ----
    int totalT = (L + 1) * A * N;
    if (idx < totalT) {
        int z = idx / (A * N);
        int r = idx - z * (A * N);
        int a = r / N;
        int j = r - a * N;
        if (z < L) {
            const float* s = pred + (((size_t)z * N + j) * A + a) * 3;
            predT4[((size_t)z * A + a) * N + j] = make_float4(s[0], s[1], s[2], 0.f);
        } else {
            const float* s = gt + ((size_t)j * A + a) * 3;
            gtT4[(size_t)a * N + j] = make_float4(s[0], s[1], s[2], 0.f);
        }
    }

    // ---- prep part ----
    if (idx >= L * N) return;
    int l = idx / N, i = idx - l * N;

    float Rg[9]; F3 cag;
    make_frame(gt + (size_t)i * A * 3, Rg, cag);
    float Rp[9]; F3 cap;
    make_frame(pred + ((size_t)l * N + i) * A * 3, Rp, cap);

    // |Rp^T(x-tp) - Rg^T(y-tg)| == |x - (M y + c)|, M = Rp Rg^T, c = tp - M tg
    float m[9];
    #pragma unroll
    for (int d = 0; d < 3; d++)
        #pragma unroll
        for (int e = 0; e < 3; e++)
            m[d*3+e] = Rp[0*3+d]*Rg[0*3+e] + Rp[1*3+d]*Rg[1*3+e] + Rp[2*3+d]*Rg[2*3+e];
    float c0 = cap.x - (m[0]*cag.x + m[1]*cag.y + m[2]*cag.z);
    float c1 = cap.y - (m[3]*cag.x + m[4]*cag.y + m[5]*cag.z);
    float c2 = cap.z - (m[6]*cag.x + m[7]*cag.y + m[8]*cag.z);

    float* o = Mc + (size_t)idx * 12;
    #pragma unroll
    for (int k = 0; k < 9; k++) o[k] = m[k];
    o[9] = c0; o[10] = c1; o[11] = c2;

    if (l == 0) {
        unsigned mm = 0;
        for (int a = 0; a < A; a++)
            if (atom_mask[(size_t)i * A + a] > 0.f) mm |= (1u << a);
        packed[i] = (int)(mm | ((unsigned)batch[i] << 16) | ((unsigned)chain[i] << 24));
        gtca[i*3] = cag.x; gtca[i*3+1] = cag.y; gtca[i*3+2] = cag.z;
    }
    if (l == L - 1) { predca[i*3] = cap.x; predca[i*3+1] = cap.y; predca[i*3+2] = cap.z; }
}

// ---------------- fape: block = (l, i-pair), lanes stride j; float4 SoA loads ----
// State bundle so the per-j body can be written once and inlined into both
// the compile-time-unrolled (N==768) and generic paths.
struct FapeState {
    float A00,A01,A02,A10,A11,A12,A20,A21,A22,Ac0,Ac1,Ac2;
    float B00,B01,B02,B10,B11,B12,B20,B21,B22,Bc0,Bc1,Bc2;
    int msk0, bat0, ch0, msk1, bat1, ch1;
    float g0x,g0y,g0z,p0x,p0y,p0z,g1x,g1y,g1z,p1x,p1y,p1z;
    float a_ss,a_so,a_cs,a_co,a_rot, ls0,lc0,ls1,lc1;
};

__device__ __forceinline__ void fape_body(
    FapeState& S, int j, int i0, int i1, bool last, int N,
    const float4* __restrict__ gtT4, const float4* __restrict__ xT4,
    const int* __restrict__ packed,
    float* __restrict__ out_final, float* __restrict__ out_rot)
{
    int pkj = packed[j];
    int mskj = pkj & 0xFFFF;
    int bj = (pkj >> 16) & 0xFF, cj = (pkj >> 24) & 0xFF;

    int mj0 = S.msk0 & mskj, mj1 = S.msk1 & mskj;
    bool pm0 = (bj == S.bat0) && (mj0 != 0);
    bool pm1 = (bj == S.bat1) && (mj1 != 0);
    float num0 = 0.f, num1 = 0.f;

    if (__any(pm0 || pm1)) {
        #pragma unroll
        for (int a = 0; a < 14; a++) {
            float4 Y = gtT4[(size_t)a * N + j];   // coalesced dwordx4
            float4 X = xT4[(size_t)a * N + j];
            float d0 = X.x - (S.A00*Y.x + S.A01*Y.y + S.A02*Y.z + S.Ac0);
            float d1 = X.y - (S.A10*Y.x + S.A11*Y.y + S.A12*Y.z + S.Ac1);
            float d2 = X.z - (S.A20*Y.x + S.A21*Y.y + S.A22*Y.z + S.Ac2);
            num0 += (float)((mj0 >> a) & 1) * fsqrt_fast(fmaxf(d0*d0+d1*d1+d2*d2, EPS));
            float e0 = X.x - (S.B00*Y.x + S.B01*Y.y + S.B02*Y.z + S.Bc0);
            float e1 = X.y - (S.B10*Y.x + S.B11*Y.y + S.B12*Y.z + S.Bc1);
            float e2 = X.z - (S.B20*Y.x + S.B21*Y.y + S.B22*Y.z + S.Bc2);
            num1 += (float)((mj1 >> a) & 1) * fsqrt_fast(fmaxf(e0*e0+e1*e1+e2*e2, EPS));
        }
    }

    float fv0 = pm0 ? num0 * frcp_fast((float)__popc((unsigned)mj0)) : 0.f;
    float fv1 = pm1 ? num1 * frcp_fast((float)__popc((unsigned)mj1)) : 0.f;

    if (last) {
        out_final[(size_t)i0 * N + j] = fv0;   // coalesced
        out_final[(size_t)i1 * N + j] = fv1;
        if (j == i0) out_rot[i0] = fv0;
        if (j == i1) out_rot[i1] = fv1;
    }
    if (j == i0) S.a_rot += fv0;
    if (j == i1) S.a_rot += fv1;
    if (pm0) {
        float cl = fminf(fv0, 10.f);
        if (S.ch0 == cj) { S.a_ss += cl; S.a_cs += 1.f; } else { S.a_so += cl; S.a_co += 1.f; }
    }
    if (pm1) {
        float cl = fminf(fv1, 10.f);
        if (S.ch1 == cj) { S.a_ss += cl; S.a_cs += 1.f; } else { S.a_so += cl; S.a_co += 1.f; }
    }
    if (last) {
        float4 CG = gtT4[(size_t)1 * N + j];   // CA of row j (atom 1)
        float4 CP = xT4[(size_t)1 * N + j];
        bool ok0 = (S.msk0 != 0) && (mskj != 0) && (j != i0);
        bool ok1 = (S.msk1 != 0) && (mskj != 0) && (j != i1);
        if (ok0) {
            float dx=S.g0x-CG.x, dy=S.g0y-CG.y, dz=S.g0z-CG.z;
            float gd = fsqrt_fast(fmaxf(dx*dx+dy*dy+dz*dz, EPS));
            if (gd < 15.f) {
                float ex=S.p0x-CP.x, ey=S.p0y-CP.y, ez=S.p0z-CP.z;
                float pd = fsqrt_fast(fmaxf(ex*ex+ey*ey+ez*ez, EPS));
                float de = fabsf(gd - pd);
                S.ls0 += ((de<0.5f?1.f:0.f)+(de<1.f?1.f:0.f)+(de<2.f?1.f:0.f)+(de<4.f?1.f:0.f))*0.25f;
                S.lc0 += 1.f;
            }
        }
        if (ok1) {
            float dx=S.g1x-CG.x, dy=S.g1y-CG.y, dz=S.g1z-CG.z;
            float gd = fsqrt_fast(fmaxf(dx*dx+dy*dy+dz*dz, EPS));
            if (gd < 15.f) {
                float ex=S.p1x-CP.x, ey=S.p1y-CP.y, ez=S.p1z-CP.z;
                float pd = fsqrt_fast(fmaxf(ex*ex+ey*ey+ez*ez, EPS));
                float de = fabsf(gd - pd);
                S.ls1 += ((de<0.5f?1.f:0.f)+(de<1.f?1.f:0.f)+(de<2.f?1.f:0.f)+(de<4.f?1.f:0.f))*0.25f;
                S.lc1 += 1.f;
            }
        }
    }
}

__global__ __launch_bounds__(256, 3) void fape_kernel(
    const float4* __restrict__ predT4, const float4* __restrict__ gtT4,
    const float* __restrict__ Mc, const int* __restrict__ packed,
    const float* __restrict__ gtca, const float* __restrict__ predca,
    float* __restrict__ part,
    float* __restrict__ out_final, float* __restrict__ out_rot,
    float* __restrict__ out_lddt,
    int L, int N)
{
    int t = threadIdx.x;
    int ib = blockIdx.x, l = blockIdx.y;
    int i0 = ib * IPB;
    int i1 = i0 + 1;
    bool last = (l == L - 1);

    FapeState S;
    // block-uniform transform loads as float4 (Mc rows are 48B, 16B-aligned)
    const float4* __restrict__ mc4 = (const float4*)(Mc + ((size_t)l * N + i0) * 12);
    float4 v0 = mc4[0], v1 = mc4[1], v2 = mc4[2], v3 = mc4[3], v4 = mc4[4], v5 = mc4[5];
    S.A00=v0.x; S.A01=v0.y; S.A02=v0.z; S.A10=v0.w; S.A11=v1.x; S.A12=v1.y;
    S.A20=v1.z; S.A21=v1.w; S.A22=v2.x; S.Ac0=v2.y; S.Ac1=v2.z; S.Ac2=v2.w;
    S.B00=v3.x; S.B01=v3.y; S.B02=v3.z; S.B10=v3.w; S.B11=v4.x; S.B12=v4.y;
    S.B20=v4.z; S.B21=v4.w; S.B22=v5.x; S.Bc0=v5.y; S.Bc1=v5.z; S.Bc2=v5.w;

    int pk0 = packed[i0], pk1 = packed[i1];
    S.msk0 = pk0 & 0xFFFF; S.bat0 = (pk0 >> 16) & 0xFF; S.ch0 = (pk0 >> 24) & 0xFF;
    S.msk1 = pk1 & 0xFFFF; S.bat1 = (pk1 >> 16) & 0xFF; S.ch1 = (pk1 >> 24) & 0xFF;

    S.g0x=S.g0y=S.g0z=S.p0x=S.p0y=S.p0z=0.f;
    S.g1x=S.g1y=S.g1z=S.p1x=S.p1y=S.p1z=0.f;
    if (last) {
        S.g0x=gtca[i0*3]; S.g0y=gtca[i0*3+1]; S.g0z=gtca[i0*3+2];
        S.p0x=predca[i0*3]; S.p0y=predca[i0*3+1]; S.p0z=predca[i0*3+2];
        S.g1x=gtca[i1*3]; S.g1y=gtca[i1*3+1]; S.g1z=gtca[i1*3+2];
        S.p1x=predca[i1*3]; S.p1y=predca[i1*3+1]; S.p1z=predca[i1*3+2];
    }

    const float4* __restrict__ xT4 = predT4 + (size_t)l * 14 * N;   // [a][j]

    S.a_ss=0.f; S.a_so=0.f; S.a_cs=0.f; S.a_co=0.f; S.a_rot=0.f;
    S.ls0=0.f; S.lc0=0.f; S.ls1=0.f; S.lc1=0.f;

    if (N == 768) {
        // compile-time trip count -> full unroll, loads pipelined across iterations
        #pragma unroll
        for (int jj = 0; jj < 3; jj++)
            fape_body(S, t + jj * 256, i0, i1, last, 768, gtT4, xT4, packed, out_final, out_rot);
    } else {
        for (int j = t; j < N; j += 256)
            fape_body(S, j, i0, i1, last, N, gtT4, xT4, packed, out_final, out_rot);
    }

    // ---- block-local reduction of 9 values (no global atomics) ----
    float vals[9];
    vals[0]=S.a_ss; vals[1]=S.a_so; vals[2]=S.a_cs; vals[3]=S.a_co; vals[4]=S.a_rot;
    vals[5]=S.ls0; vals[6]=S.lc0; vals[7]=S.ls1; vals[8]=S.lc1;
    #pragma unroll
    for (int k = 0; k < 9; k++)
        for (int o = 32; o > 0; o >>= 1) vals[k] += __shfl_down(vals[k], o, 64);

    __shared__ float red[4][9];
    int wave = t >> 6, lane = t & 63;
    if (lane == 0) {
        #pragma unroll
        for (int k = 0; k < 9; k++) red[wave][k] = vals[k];
    }
    __syncthreads();
    if (t == 0) {
        float v[9];
        #pragma unroll
        for (int k = 0; k < 9; k++)
            v[k] = red[0][k] + red[1][k] + red[2][k] + red[3][k];
        float* p = part + ((size_t)l * (N / IPB) + ib) * 8;
        p[0]=v[0]; p[1]=v[1]; p[2]=v[2]; p[3]=v[3]; p[4]=v[4];
        if (last) {
            out_lddt[i0] = v[5] / fmaxf(v[6], 1e-6f);
            out_lddt[i1] = v[7] / fmaxf(v[8], 1e-6f);
        }
    }
}

// ---------------- reduce: sum per-block partials -> scalars ----------------
__global__ __launch_bounds__(256) void reduce_kernel(
    const int* __restrict__ packed, const float* __restrict__ part,
    float* __restrict__ out, int L, int N)
{
    int t = threadIdx.x;
    int BPL = N / IPB;
    float ss[4]={0,0,0,0}, so[4]={0,0,0,0}, rt[4]={0,0,0,0};
    float cs=0.f, co=0.f;
    for (int b = t; b < BPL * L; b += 256) {
        int l = b / BPL;
        const float* p = part + (size_t)b * 8;
        ss[l] += p[0]; so[l] += p[1]; rt[l] += p[4];
        if (l == 0) { cs += p[2]; co += p[3]; }
    }
    float nr = 0.f;
    for (int i = t; i < N; i += 256)
        nr += ((packed[i] & 0xFFFF) != 0) ? 1.f : 0.f;

    __shared__ float red[4];
    int wave = t >> 6, lane = t & 63;
    float vals[11];
    vals[0]=cs; vals[1]=co; vals[2]=nr;
    for (int l = 0; l < L; l++) { vals[3+l]=ss[l]; vals[3+L+l]=so[l]; vals[3+2*L+l]=rt[l]; }
    float res[11];
    for (int k = 0; k < 3 + 3*L; k++) {
        float v = vals[k];
        for (int o = 32; o > 0; o >>= 1) v += __shfl_down(v, o, 64);
        __syncthreads();
        if (lane == 0) red[wave] = v;
        __syncthreads();
        res[k] = red[0] + red[1] + red[2] + red[3];
    }
    if (t == 0) {
        float csf = fmaxf(res[0], 1e-6f);
        float cof = fmaxf(res[1], 1e-6f);
        float nrm = fmaxf(res[2], 1e-6f);
        for (int l = 0; l < L; l++) {
            out[l]     = res[3+l] / csf / 10.f + res[3+L+l] / cof / 10.f;
            out[L + l] = res[3+2*L+l] / nrm;
        }
    }
}

extern "C" void kernel_launch(void* const* d_in, const int* in_sizes, int n_in,
                              void* d_out, int out_size, void* d_ws, size_t ws_size,
                              hipStream_t stream)
{
    const float* pred      = (const float*)d_in[0];
    const float* gt        = (const float*)d_in[1];
    const float* atom_mask = (const float*)d_in[2];
    const int*   batch     = (const int*)d_in[3];
    const int*   chain     = (const int*)d_in[4];

    int N = in_sizes[3];
    int A = in_sizes[2] / N;
    int L = in_sizes[0] / (N * A * 3);

    float* out = (float*)d_out;
    float* out_final = out + 2 * L;
    float* out_rot   = out_final + (size_t)N * N;
    float* out_lddt  = out_rot + N;

    float* ws = (float*)d_ws;
    float* Mc      = ws;                                  // L*N*12
    float* gtca    = Mc + (size_t)L * N * 12;             // N*3
    float* predca  = gtca + (size_t)N * 3;                // N*3
    float* part    = predca + (size_t)N * 3;              // (L*N/IPB)*8
    float4* predT4 = (float4*)(part + (size_t)L * (N / IPB) * 8);  // L*A*N float4
    float4* gtT4   = predT4 + (size_t)L * A * N;          // A*N float4
    int*   packed  = (int*)(gtT4 + (size_t)A * N);        // N

    int totalT = (L + 1) * A * N;
    prep_all_kernel<<<(totalT + 255) / 256, 256, 0, stream>>>(
        pred, gt, atom_mask, batch, chain,
        Mc, packed, gtca, predca, predT4, gtT4, L, N, A);

    dim3 grid(N / IPB, L);   // 384 x 2 = 768 blocks = 3 per CU
    fape_kernel<<<grid, 256, 0, stream>>>(
        predT4, gtT4, Mc, packed, gtca, predca, part,
        out_final, out_rot, out_lddt, L, N);

    reduce_kernel<<<1, 256, 0, stream>>>(packed, part, out, L, N);
}